// Round 2
// baseline (42.758 us; speedup 1.0000x reference)
//
#include <hip/hip_runtime.h>
#include <cmath>

#define NP 64    // patients
#define NM 16    // mats per patient
#define NA 512   // input_size (row length)
#define NB 128   // rows per mat (columns of x's last dim)
#define H1 256
#define H2 256
#define NC 32

__device__ __forceinline__ float sigmoid_(float x) {
    return 1.0f / (1.0f + __expf(-x));
}

// One block per patient. Only x[p, NM-1, :, NB-1] contributes to the output.
extern "C" __global__ __launch_bounds__(256)
void rnn_fused(const float* __restrict__ x,
               const float* __restrict__ W1, const float* __restrict__ b1,
               const float* __restrict__ W_ih,
               const float* __restrict__ b_ih, const float* __restrict__ b_hh,
               const float* __restrict__ W3, const float* __restrict__ b3,
               float* __restrict__ out)
{
    __shared__ float row[NA];    // 2 KB
    __shared__ float h1s[H1];    // 1 KB
    __shared__ float hs[H2];     // 1 KB
    __shared__ float logits[NC];

    const int p = blockIdx.x;
    const int t = threadIdx.x;

    // ---- gather the single relevant row: x[p, NM-1, a, NB-1], stride NB ----
    const size_t abase = ((size_t)p * NM + (NM - 1)) * NA;
    for (int a = t; a < NA; a += 256)
        row[a] = x[(abase + a) * NB + (NB - 1)];
    __syncthreads();

    // ---- fc1 + ReLU: h1[t] = relu(W1[t,:] . row + b1[t]) ----
    {
        const float4* w = (const float4*)(W1 + (size_t)t * NA);
        const float4* r = (const float4*)row;
        float acc = 0.f;
        #pragma unroll 8
        for (int k = 0; k < NA / 4; ++k) {
            float4 wv = w[k], rv = r[k];
            acc = fmaf(wv.x, rv.x, acc);
            acc = fmaf(wv.y, rv.y, acc);
            acc = fmaf(wv.z, rv.z, acc);
            acc = fmaf(wv.w, rv.w, acc);
        }
        h1s[t] = fmaxf(acc + b1[t], 0.f);
    }
    __syncthreads();

    // ---- 1-step LSTM with h0=c0=0: gates i,g,o (f unused since c0=0) ----
    {
        float ai = b_ih[t]            + b_hh[t];
        float ag = b_ih[2 * H2 + t]   + b_hh[2 * H2 + t];
        float ao = b_ih[3 * H2 + t]   + b_hh[3 * H2 + t];
        const float4* wi = (const float4*)(W_ih + (size_t)t * H1);
        const float4* wg = (const float4*)(W_ih + (size_t)(2 * H2 + t) * H1);
        const float4* wo = (const float4*)(W_ih + (size_t)(3 * H2 + t) * H1);
        const float4* hv = (const float4*)h1s;
        #pragma unroll 8
        for (int k = 0; k < H1 / 4; ++k) {
            float4 h4 = hv[k];
            float4 a4 = wi[k];
            float4 g4 = wg[k];
            float4 o4 = wo[k];
            ai = fmaf(a4.x, h4.x, fmaf(a4.y, h4.y, fmaf(a4.z, h4.z, fmaf(a4.w, h4.w, ai))));
            ag = fmaf(g4.x, h4.x, fmaf(g4.y, h4.y, fmaf(g4.z, h4.z, fmaf(g4.w, h4.w, ag))));
            ao = fmaf(o4.x, h4.x, fmaf(o4.y, h4.y, fmaf(o4.z, h4.z, fmaf(o4.w, h4.w, ao))));
        }
        float c = sigmoid_(ai) * tanhf(ag);
        float h = sigmoid_(ao) * tanhf(c);
        hs[t] = fmaxf(h, 0.f);
    }
    __syncthreads();

    // ---- fc3: 32 classes, 8 lanes per class ----
    {
        const int g = t >> 3;   // class 0..31
        const int l = t & 7;    // lane within class group
        const float4* w  = (const float4*)(W3 + (size_t)g * H2);
        const float4* hv = (const float4*)hs;
        float acc = 0.f;
        #pragma unroll
        for (int j = 0; j < 8; ++j) {
            float4 wv = w[l + 8 * j];
            float4 h4 = hv[l + 8 * j];
            acc = fmaf(wv.x, h4.x, acc);
            acc = fmaf(wv.y, h4.y, acc);
            acc = fmaf(wv.z, h4.z, acc);
            acc = fmaf(wv.w, h4.w, acc);
        }
        acc += __shfl_down(acc, 4, 64);
        acc += __shfl_down(acc, 2, 64);
        acc += __shfl_down(acc, 1, 64);
        if (l == 0) logits[g] = acc + b3[g];
    }
    __syncthreads();

    // ---- softmax over 32 classes (lanes 0..31 of wave 0) ----
    if (t < NC) {
        float v = logits[t];
        float m = v;
        #pragma unroll
        for (int off = 16; off; off >>= 1) m = fmaxf(m, __shfl_xor(m, off, 64));
        float e = __expf(v - m);
        float s = e;
        #pragma unroll
        for (int off = 16; off; off >>= 1) s += __shfl_xor(s, off, 64);
        out[p * NC + t] = e / s;
    }
}

extern "C" void kernel_launch(void* const* d_in, const int* in_sizes, int n_in,
                              void* d_out, int out_size, void* d_ws, size_t ws_size,
                              hipStream_t stream) {
    const float* x    = (const float*)d_in[0];
    const float* W1   = (const float*)d_in[1];
    const float* b1   = (const float*)d_in[2];
    const float* W_ih = (const float*)d_in[3];
    // d_in[4] = W_hh: unused (h0 = 0 kills the recurrent term)
    const float* b_ih = (const float*)d_in[5];
    const float* b_hh = (const float*)d_in[6];
    const float* W3   = (const float*)d_in[7];
    const float* b3   = (const float*)d_in[8];
    float* out = (float*)d_out;

    hipLaunchKernelGGL(rnn_fused, dim3(NP), dim3(256), 0, stream,
                       x, W1, b1, W_ih, b_ih, b_hh, W3, b3, out);
}